// Round 3
// baseline (302.781 us; speedup 1.0000x reference)
//
#include <hip/hip_runtime.h>
#include <hip/hip_bf16.h>
#include <stdint.h>

#define DIM 1024
#define ALPHA 7.18f
#define INV_N (1.0f/32768.0f)
#define NM1 32767.0f
#define LOG2E 1.44269504088896f
#define LN2 0.693147180559945f

typedef __attribute__((ext_vector_type(8))) short bfrag8;
typedef __attribute__((ext_vector_type(4))) float f32x4;

typedef const __attribute__((address_space(1))) void gv_t;
typedef __attribute__((address_space(3))) void lv_t;

__device__ __forceinline__ unsigned f2bf_bits(float f) {
    unsigned u = __float_as_uint(f);
    return (u + 0x7fffu + ((u >> 16) & 1u)) >> 16;
}

// ---------------- K1: pure-stream column sums + sq-sum -------------------
// 2048 blocks: rg = bid>>2 (64-row group), cq = bid&3 (256-col quarter).
// 512 threads: c4 = tid&63 (float4 within quarter), rq = tid>>6 (8 rows).
__global__ __launch_bounds__(512)
void k1_colsum(const float* __restrict__ outputs, const int* __restrict__ indices,
               const int* __restrict__ assignment, float* __restrict__ mean_sums,
               unsigned* __restrict__ counts, float* __restrict__ scalars,
               int* __restrict__ own_g) {
    __shared__ int sown[64];
    __shared__ int suni;
    __shared__ float4 spart[8][64];
    __shared__ float ssq[8];
    const int tid = threadIdx.x;
    const int rg = blockIdx.x >> 2, cq = blockIdx.x & 3;
    const int row0 = rg * 64;
    if (tid == 0) suni = 1;
    if (tid < 64) {
        int m = assignment[indices[row0 + tid]];
        sown[tid] = m;
        if (cq == 0) { own_g[row0 + tid] = m; atomicAdd(&counts[m], 1u); }
    }
    __syncthreads();
    if (tid < 63 && sown[tid] != sown[tid + 1]) suni = 0;
    __syncthreads();

    const int c4 = tid & 63;
    const int rq = tid >> 6;
    const float* gp = outputs + (size_t)(row0 + rq * 8) * DIM + cq * 256 + c4 * 4;
    float4 s4 = {0.f, 0.f, 0.f, 0.f};
    float sq = 0.f;

    if (suni) {
        #pragma unroll
        for (int r = 0; r < 8; ++r) {
            float4 v = *(const float4*)(gp + (size_t)r * DIM);
            sq = fmaf(v.x, v.x, sq); sq = fmaf(v.y, v.y, sq);
            sq = fmaf(v.z, v.z, sq); sq = fmaf(v.w, v.w, sq);
            s4.x += v.x; s4.y += v.y; s4.z += v.z; s4.w += v.w;
        }
        spart[rq][c4] = s4;
        __syncthreads();
        if (rq == 0) {
            #pragma unroll
            for (int r = 1; r < 8; ++r) {
                float4 o = spart[r][c4];
                s4.x += o.x; s4.y += o.y; s4.z += o.z; s4.w += o.w;
            }
            float* dst = mean_sums + (size_t)sown[0] * DIM + cq * 256 + c4 * 4;
            atomicAdd(dst + 0, s4.x); atomicAdd(dst + 1, s4.y);
            atomicAdd(dst + 2, s4.z); atomicAdd(dst + 3, s4.w);
        }
    } else {
        int curm = sown[rq * 8];
        for (int r = 0; r < 8; ++r) {
            float4 v = *(const float4*)(gp + (size_t)r * DIM);
            int m = sown[rq * 8 + r];
            if (m != curm) {
                float* dst = mean_sums + (size_t)curm * DIM + cq * 256 + c4 * 4;
                atomicAdd(dst + 0, s4.x); atomicAdd(dst + 1, s4.y);
                atomicAdd(dst + 2, s4.z); atomicAdd(dst + 3, s4.w);
                s4 = (float4){0.f, 0.f, 0.f, 0.f};
                curm = m;
            }
            sq = fmaf(v.x, v.x, sq); sq = fmaf(v.y, v.y, sq);
            sq = fmaf(v.z, v.z, sq); sq = fmaf(v.w, v.w, sq);
            s4.x += v.x; s4.y += v.y; s4.z += v.z; s4.w += v.w;
        }
        float* dst = mean_sums + (size_t)curm * DIM + cq * 256 + c4 * 4;
        atomicAdd(dst + 0, s4.x); atomicAdd(dst + 1, s4.y);
        atomicAdd(dst + 2, s4.z); atomicAdd(dst + 3, s4.w);
        __syncthreads();
    }

    #pragma unroll
    for (int mk = 32; mk; mk >>= 1) sq += __shfl_xor(sq, mk, 64);
    if ((tid & 63) == 0) ssq[tid >> 6] = sq;
    __syncthreads();
    if (tid == 0) {
        float s = 0.f;
        #pragma unroll
        for (int w = 0; w < 8; ++w) s += ssq[w];
        atomicAdd(&scalars[0], s);
    }
}

// ---------------- K2: means -> bf16 K-tiled B', ||mu||^2, var term -------
// B' layout: tt*32768 + m*64 + (kc ^ ((m>>1)&3))*16 + half*8
__global__ __launch_bounds__(256)
void k2_means(const float* __restrict__ mean_sums, const unsigned* __restrict__ counts,
              unsigned short* __restrict__ b_kt, float* __restrict__ msq,
              float* __restrict__ scalars) {
    const int m = blockIdx.x, t = threadIdx.x;
    const float* row = mean_sums + (size_t)m * DIM;
    float4 v = *(const float4*)(row + t * 4);
    float4 mu = {v.x * (1.0f/64.0f), v.y * (1.0f/64.0f), v.z * (1.0f/64.0f), v.w * (1.0f/64.0f)};
    const int tt = t >> 3, kc = (t >> 1) & 3, half = t & 1;
    unsigned lo = f2bf_bits(mu.x) | (f2bf_bits(mu.y) << 16);
    unsigned hi = f2bf_bits(mu.z) | (f2bf_bits(mu.w) << 16);
    *(uint2*)((char*)b_kt + tt * 32768 + m * 64 + ((kc ^ ((m >> 1) & 3)) << 4) + half * 8)
        = make_uint2(lo, hi);
    float sq = fmaf(mu.x, mu.x, fmaf(mu.y, mu.y, fmaf(mu.z, mu.z, mu.w * mu.w)));
    #pragma unroll
    for (int mk = 32; mk; mk >>= 1) sq += __shfl_xor(sq, mk, 64);
    __shared__ float sw[4];
    if ((t & 63) == 0) sw[t >> 6] = sq;
    __syncthreads();
    if (t == 0) {
        float s = sw[0] + sw[1] + sw[2] + sw[3];
        msq[m] = s;
        atomicAdd(&scalars[1], ((float)counts[m] - 128.0f) * s);
    }
}

// ---------------- K3: scalars + output init ------------------------------
__global__ __launch_bounds__(512)
void k3_finalize(float* __restrict__ scalars, const float* __restrict__ msq,
                 const unsigned* __restrict__ counts, const float* __restrict__ loss_vector,
                 const float* __restrict__ loss_count, float* __restrict__ msl,
                 float* __restrict__ out) {
    const int t = threadIdx.x;
    float var_sum = scalars[0] + scalars[1];
    float inv_std = -NM1 / (2.0f * var_sum);
    msl[t] = msq[t] * inv_std * LOG2E;
    out[1 + t] = loss_vector[t] * INV_N;
    out[513 + t] = loss_count[t] + (float)counts[t];
    if (t == 0) {
        out[0] = 0.0f;
        out[1025] = var_sum / NM1;
        scalars[2] = inv_std;
    }
}

// ---------------- K4: fused GEMM + softmax-denom + loss ------------------
// 256 blocks, 128 rows x 512 cols, 512 threads = 8 waves (2x4).
// Per-wave 64x128 output (acc[4][8]). BK=32, dbuf LDS, B' via gload_lds.
__global__ __launch_bounds__(512, 2)
void k4_gemm(const float* __restrict__ outputs, const unsigned short* __restrict__ b_kt,
             const float* __restrict__ msl, const float* __restrict__ scalars,
             const int* __restrict__ own_g, float* __restrict__ out) {
    __shared__ short lA[2][128 * 32];   // 8 KB each
    __shared__ short lB[2][512 * 32];   // 32 KB each
    __shared__ float red_sum[128][4];
    __shared__ float red_own[128][4];

    const int tid  = threadIdx.x;
    const int lane = tid & 63;
    const int wid  = tid >> 6;
    const int wm   = wid >> 2;      // 0..1 : 64-row halves
    const int wn   = wid & 3;       // 0..3 : 128-col quarters
    const int brow = blockIdx.x * 128;

    // A staging: thread -> rows rA and rA+64, k-chunk kq (4 floats)
    const int rA = tid >> 3;        // 0..63
    const int kq = tid & 7;
    const float* gA = outputs + (size_t)(brow + rA) * DIM + kq * 4;
    const int aw0 = rA * 64 + ((((kq >> 1)) ^ ((rA >> 1) & 3)) << 4) + ((kq & 1) << 3);
    const int aw1 = aw0 + 64 * 64;  // row rA+64 (same swizzle phase)

    // fragment read bases
    const int arow0 = wm * 64 + (lane & 15);
    const int ar_base = arow0 * 64 + (((lane >> 4) ^ ((arow0 >> 1) & 3)) << 4);
    const int bcol = wn * 128 + (lane & 15);
    const int br_byte = bcol * 64 + (((lane >> 4) ^ ((bcol >> 1) & 3)) << 4);

    const char* bbase = (const char*)b_kt;

    f32x4 acc[4][8];
    #pragma unroll
    for (int i = 0; i < 4; ++i)
        #pragma unroll
        for (int j = 0; j < 8; ++j)
            acc[i][j] = (f32x4){0.f, 0.f, 0.f, 0.f};

    // ---- prologue: stage tile 0
    #pragma unroll
    for (int i = 0; i < 4; ++i) {
        const char* gsrc = bbase + (wid * 4 + i) * 1024 + lane * 16;
        char* ldst = (char*)&lB[0][0] + (wid * 4 + i) * 1024;
        __builtin_amdgcn_global_load_lds((gv_t*)gsrc, (lv_t*)ldst, 16, 0, 0);
    }
    {
        float4 a0 = *(const float4*)gA;
        float4 a1 = *(const float4*)(gA + 64 * DIM);
        unsigned l0 = f2bf_bits(a0.x) | (f2bf_bits(a0.y) << 16);
        unsigned h0 = f2bf_bits(a0.z) | (f2bf_bits(a0.w) << 16);
        unsigned l1 = f2bf_bits(a1.x) | (f2bf_bits(a1.y) << 16);
        unsigned h1 = f2bf_bits(a1.z) | (f2bf_bits(a1.w) << 16);
        *(uint2*)((char*)&lA[0][0] + aw0) = make_uint2(l0, h0);
        *(uint2*)((char*)&lA[0][0] + aw1) = make_uint2(l1, h1);
    }
    __syncthreads();

    int cur = 0;
    for (int t = 0; t < 32; ++t) {
        const bool has_next = (t + 1) < 32;
        float4 a0n, a1n;
        if (has_next) {
            a0n = *(const float4*)(gA + (t + 1) * 32);              // issue early
            a1n = *(const float4*)(gA + 64 * DIM + (t + 1) * 32);
            #pragma unroll
            for (int i = 0; i < 4; ++i) {
                const char* gsrc = bbase + (size_t)(t + 1) * 32768 + (wid * 4 + i) * 1024 + lane * 16;
                char* ldst = (char*)&lB[cur ^ 1][0] + (wid * 4 + i) * 1024;
                __builtin_amdgcn_global_load_lds((gv_t*)gsrc, (lv_t*)ldst, 16, 0, 0);
            }
        }

        const char* pa = (const char*)&lA[cur][0] + ar_base;
        const char* pb = (const char*)&lB[cur][0] + br_byte;
        bfrag8 af[4];
        #pragma unroll
        for (int fm = 0; fm < 4; ++fm) af[fm] = *(const bfrag8*)(pa + fm * 1024);
        #pragma unroll
        for (int fn = 0; fn < 8; ++fn) {
            bfrag8 bf = *(const bfrag8*)(pb + fn * 1024);
            #pragma unroll
            for (int fm = 0; fm < 4; ++fm)
                acc[fm][fn] = __builtin_amdgcn_mfma_f32_16x16x32_bf16(af[fm], bf, acc[fm][fn], 0, 0, 0);
        }

        if (has_next) {                                            // write late
            unsigned l0 = f2bf_bits(a0n.x) | (f2bf_bits(a0n.y) << 16);
            unsigned h0 = f2bf_bits(a0n.z) | (f2bf_bits(a0n.w) << 16);
            unsigned l1 = f2bf_bits(a1n.x) | (f2bf_bits(a1n.y) << 16);
            unsigned h1 = f2bf_bits(a1n.z) | (f2bf_bits(a1n.w) << 16);
            *(uint2*)((char*)&lA[cur ^ 1][0] + aw0) = make_uint2(l0, h0);
            *(uint2*)((char*)&lA[cur ^ 1][0] + aw1) = make_uint2(l1, h1);
        }
        __syncthreads();
        cur ^= 1;
    }

    // ---- epilogue: exps, row sums, own capture
    float mslv[8];
    #pragma unroll
    for (int fn = 0; fn < 8; ++fn) mslv[fn] = msl[bcol + fn * 16];
    const float inv_std = scalars[2];
    const float c2k = -2.0f * inv_std * LOG2E;
    int ownv[4][4];
    #pragma unroll
    for (int fm = 0; fm < 4; ++fm)
        #pragma unroll
        for (int rg = 0; rg < 4; ++rg)
            ownv[fm][rg] = own_g[brow + wm * 64 + fm * 16 + ((lane >> 4) << 2) + rg];

    #pragma unroll
    for (int fm = 0; fm < 4; ++fm) {
        #pragma unroll
        for (int rg = 0; rg < 4; ++rg) {
            float sum = 0.f, oa = -1e30f;
            int ownr = ownv[fm][rg];
            #pragma unroll
            for (int fn = 0; fn < 8; ++fn) {
                float dot = acc[fm][fn][rg];
                float arg = fmaf(c2k, dot, mslv[fn]);
                sum += exp2f(arg);
                bool isown = (bcol + fn * 16) == ownr;
                oa = isown ? arg : oa;
            }
            #pragma unroll
            for (int mk = 1; mk < 16; mk <<= 1) {
                sum += __shfl_xor(sum, mk, 64);
                oa = fmaxf(oa, __shfl_xor(oa, mk, 64));
            }
            if ((lane & 15) == 0) {
                int r_in = wm * 64 + fm * 16 + ((lane >> 4) << 2) + rg;
                red_sum[r_in][wn] = sum;
                red_own[r_in][wn] = oa;
            }
        }
    }
    __syncthreads();

    if (tid < 128) {   // waves 0,1 finish rows 0..63 / 64..127
        float s = red_sum[tid][0] + red_sum[tid][1] + red_sum[tid][2] + red_sum[tid][3];
        float oa = fmaxf(fmaxf(red_own[tid][0], red_own[tid][1]),
                         fmaxf(red_own[tid][2], red_own[tid][3]));
        float denom = s - exp2f(oa);
        float per_loss = fmaxf(ALPHA + LN2 * (log2f(denom) - oa), 0.f);
        int ownr = own_g[brow + tid];
        float ls = per_loss;
        #pragma unroll
        for (int mk = 1; mk < 64; mk <<= 1) ls += __shfl_xor(ls, mk, 64);
        int own0 = __shfl(ownr, 0, 64);
        if (__all(ownr == own0)) {
            if (lane == 0) atomicAdd(&out[1 + own0], ls * INV_N);
        } else {
            atomicAdd(&out[1 + ownr], per_loss * INV_N);
        }
        if (lane == 0) atomicAdd(&out[0], ls * INV_N);
    }
}

extern "C" void kernel_launch(void* const* d_in, const int* in_sizes, int n_in,
                              void* d_out, int out_size, void* d_ws, size_t ws_size,
                              hipStream_t stream) {
    const float* outputs     = (const float*)d_in[0];
    const int*   indices     = (const int*)d_in[1];
    const int*   assignment  = (const int*)d_in[2];
    const float* loss_vector = (const float*)d_in[3];
    const float* loss_count  = (const float*)d_in[4];
    float* out = (float*)d_out;

    char* ws = (char*)d_ws;
    float*          mean_sums = (float*)ws;                       // 2 MB
    unsigned*       counts    = (unsigned*)(ws + 2097152);        // 2 KB
    float*          scalars   = (float*)(ws + 2099200);           // 256 B
    const size_t    ZB        = 2099456;
    unsigned short* b_kt      = (unsigned short*)(ws + 2101248);  // 1 MB (K-tiled means)
    float*          msq       = (float*)(ws + 3149824);           // 2 KB
    float*          msl       = (float*)(ws + 3151872);           // 2 KB
    int*            own_g     = (int*)(ws + 3153920);             // 128 KB

    hipMemsetAsync(d_ws, 0, ZB, stream);
    hipLaunchKernelGGL(k1_colsum, dim3(2048), dim3(512), 0, stream,
                       outputs, indices, assignment, mean_sums, counts, scalars, own_g);
    hipLaunchKernelGGL(k2_means, dim3(512), dim3(256), 0, stream,
                       mean_sums, counts, b_kt, msq, scalars);
    hipLaunchKernelGGL(k3_finalize, dim3(1), dim3(512), 0, stream,
                       scalars, msq, counts, loss_vector, loss_count, msl, out);
    hipLaunchKernelGGL(k4_gemm, dim3(256), dim3(512), 0, stream,
                       outputs, b_kt, msl, scalars, own_g, out);
}